// Round 5
// baseline (518.448 us; speedup 1.0000x reference)
//
#include <hip/hip_runtime.h>

#define N_NODES 100000
#define N_EDGES 1600000
#define D_FEAT  128
#define C_CLS   40
#define LN_EPS  1e-5f

#define RPB   256                         // rows per bucket
#define NBKT  ((N_NODES + RPB - 1) / RPB) // 391
#define BCAP  6144                        // padded slots/bucket (mean 4096, sigma~64)
#define TILE_E 4096                       // edges per bin block (round-0 proven)
#define EBLK  ((N_EDGES + TILE_E - 1) / TILE_E)  // 391
#define CONVB (N_NODES * 64 / 256)        // 25000 conv blocks

typedef __attribute__((ext_vector_type(8))) short short8;
typedef __attribute__((ext_vector_type(4))) float floatx4;
typedef __attribute__((ext_vector_type(2))) int   intx2;
typedef __attribute__((ext_vector_type(4))) unsigned uintx4;

// ---------- bf16 pack/unpack (storage only; accumulate fp32) ----------
__device__ inline unsigned pack_bf2(float x, float y) {
    unsigned xi = __float_as_uint(x);
    unsigned yi = __float_as_uint(y);
    unsigned lo = (xi + 0x7fffu + ((xi >> 16) & 1u)) >> 16;
    unsigned hi = (yi + 0x7fffu + ((yi >> 16) & 1u)) & 0xffff0000u;
    return lo | hi;
}
__device__ inline float bf_lo(unsigned v) { return __uint_as_float(v << 16); }
__device__ inline float bf_hi(unsigned v) { return __uint_as_float(v & 0xffff0000u); }
__device__ inline short bf16_of(float x) {
    unsigned u = __float_as_uint(x);
    return (short)((u + 0x7fffu + ((u >> 16) & 1u)) >> 16);
}

// ---- fused: blocks [0,EBLK) bin edges into buckets (+ global degree count);
// rest convert feat.  csr_tmp[b*BCAP + slot] = (lrow<<17) | col
__global__ __launch_bounds__(256) void convbin_k(const float* __restrict__ feat,
                                                 unsigned* __restrict__ hb,
                                                 const int* __restrict__ row,
                                                 const int* __restrict__ col,
                                                 int* __restrict__ bktsz,
                                                 int* __restrict__ deg,
                                                 int* __restrict__ csr_tmp) {
    int t = threadIdx.x;
    if (blockIdx.x >= EBLK) {
        int i = (blockIdx.x - EBLK) * 256 + t;       // over N*64
        float2 v = ((const float2*)feat)[i];
        hb[i] = pack_bf2(v.x, v.y);
        return;
    }
    __shared__ int hist[NBKT];
    __shared__ int cbase[NBKT];
    int tile = blockIdx.x * TILE_E;
    for (int i = t; i < NBKT; i += 256) hist[i] = 0;
    __syncthreads();
    int r[16], c[16], pos[16];
    #pragma unroll
    for (int k = 0; k < 16; k++) {
        int e = tile + k * 256 + t;
        if (e < N_EDGES) {
            r[k] = row[e]; c[k] = col[e];
            pos[k] = atomicAdd(&hist[r[k] / RPB], 1);
            atomicAdd(&deg[r[k]], 1);                // replaces refineA's histogram
        } else r[k] = -1;
    }
    __syncthreads();
    for (int i = t; i < NBKT; i += 256) {
        int h = hist[i];
        cbase[i] = h ? atomicAdd(&bktsz[i], h) : 0;
    }
    __syncthreads();
    #pragma unroll
    for (int k = 0; k < 16; k++) {
        if (r[k] >= 0) {
            int b = r[k] / RPB;
            int slot = cbase[b] + pos[k];
            if (slot < BCAP)   // statistically impossible overflow guard
                csr_tmp[b * BCAP + slot] = ((r[k] & (RPB - 1)) << 17) | c[k];
        }
    }
}

// ---- rowscan: per-bucket LDS scan of degrees -> rowinfo/dinv/selfc (tiny) ----
__global__ __launch_bounds__(256) void rowscan_k(const int* __restrict__ deg,
                                                 int2* __restrict__ rowinfo,
                                                 float* __restrict__ dinv,
                                                 float* __restrict__ selfc) {
    __shared__ int psc[RPB];
    int b = blockIdx.x, t = threadIdx.x;
    int r = b * RPB + t;
    int v = (r < N_NODES) ? deg[r] : 0;
    psc[t] = v;
    __syncthreads();
    for (int off = 1; off < 256; off <<= 1) {
        int x = (t >= off) ? psc[t - off] : 0;
        __syncthreads();
        psc[t] += x;
        __syncthreads();
    }
    if (r < N_NODES) {
        int start = b * BCAP + psc[t] - v;     // exclusive prefix, bucket-local
        float d = rsqrtf((float)v + 1.0f);
        rowinfo[r] = make_int2(start, start + v);
        dinv[r]    = d;
        selfc[r]   = 0.5f + 0.5f * d * d;
    }
}

// ---- refine B: scatter edges to final CSR with full weight ----
// bucket-ordered source + bucket-local destinations => write locality
__global__ __launch_bounds__(256) void refineB_k(const int* __restrict__ csr_tmp,
                                                 const int* __restrict__ bktsz,
                                                 const int2* __restrict__ rowinfo,
                                                 const float* __restrict__ dinv,
                                                 int2* __restrict__ csr) {
    __shared__ int   cur[RPB];
    __shared__ float dl[RPB];
    int b = blockIdx.x, t = threadIdx.x;
    int r0 = b * RPB;
    int nrows = min(RPB, N_NODES - r0);
    if (t < nrows) {
        cur[t] = rowinfo[r0 + t].x;
        dl[t]  = dinv[r0 + t];
    }
    __syncthreads();
    int cnt = bktsz[b];
    const int* base = csr_tmp + b * BCAP;
    for (int i = t; i < cnt; i += 256) {
        int pk = base[i];
        int lr = pk >> 17;
        int c  = pk & 0x1FFFF;
        int p = atomicAdd(&cur[lr], 1);
        float w = (0.5f * dl[lr]) * dinv[c];
        csr[p] = make_int2(c, __float_as_int(w));
    }
}

// ---------------- propagation: 16 lanes per node (4 nodes/wave), uint4 lane
// payload.  Non-temporal loads for the zero-reuse csr/rowinfo/selfc streams and
// non-temporal stores for hout keep L2 reserved for the gather-reused hin.
__global__ __launch_bounds__(256) void prop_bf_k(const unsigned* __restrict__ hin,
                                                 unsigned* __restrict__ hout,
                                                 const int2* __restrict__ rowinfo,
                                                 const int2* __restrict__ csr,
                                                 const float* __restrict__ selfc) {
    int t = threadIdx.x;
    int wave = t >> 6, lane = t & 63;
    int q   = lane >> 4;               // quarter-wave id: which of 4 nodes
    int sub = lane & 15;               // 16 lanes x uint4 = 256 B per node
    int node = blockIdx.x * 16 + wave * 4 + q;   // N % 16 == 0
    const uintx4* hin4 = (const uintx4*)hin;
    const intx2*  csr2 = (const intx2*)csr;

    uintx4 hv = hin4[(unsigned)node * 16 + sub];
    float sc = __builtin_nontemporal_load(selfc + node);
    float acc[8];
    acc[0] = bf_lo(hv.x) * sc; acc[1] = bf_hi(hv.x) * sc;
    acc[2] = bf_lo(hv.y) * sc; acc[3] = bf_hi(hv.y) * sc;
    acc[4] = bf_lo(hv.z) * sc; acc[5] = bf_hi(hv.z) * sc;
    acc[6] = bf_lo(hv.w) * sc; acc[7] = bf_hi(hv.w) * sc;

    intx2 ri = __builtin_nontemporal_load((const intx2*)rowinfo + node);
    int j = ri.x, end = ri.y;
    int base = ri.x;                   // always a valid csr index for this row region

    intx2 e[8];
    #pragma unroll
    for (int k = 0; k < 8; k++) {
        int idx = (j + k < end) ? j + k : base;
        e[k] = __builtin_nontemporal_load(csr2 + idx);
    }

    while (__any(j < end)) {
        // issue gathers for current chunk (predicated: dummies -> node 0, w=0)
        uintx4 g[8];
        float w[8];
        #pragma unroll
        for (int k = 0; k < 8; k++) {
            bool val = (j + k < end);
            int  c   = val ? e[k].x : 0;
            w[k]     = val ? __int_as_float(e[k].y) : 0.0f;
            g[k] = hin4[(unsigned)c * 16 + sub];
        }
        int j2 = j + 8;
        // prefetch next chunk's csr under the outstanding gathers
        #pragma unroll
        for (int k = 0; k < 8; k++) {
            int idx = (j2 + k < end) ? j2 + k : base;
            e[k] = __builtin_nontemporal_load(csr2 + idx);
        }
        #pragma unroll
        for (int k = 0; k < 8; k++) {
            acc[0] += w[k] * bf_lo(g[k].x); acc[1] += w[k] * bf_hi(g[k].x);
            acc[2] += w[k] * bf_lo(g[k].y); acc[3] += w[k] * bf_hi(g[k].y);
            acc[4] += w[k] * bf_lo(g[k].z); acc[5] += w[k] * bf_hi(g[k].z);
            acc[6] += w[k] * bf_lo(g[k].w); acc[7] += w[k] * bf_hi(g[k].w);
        }
        j = j2;
    }

    uintx4 o;
    o.x = pack_bf2(acc[0], acc[1]);
    o.y = pack_bf2(acc[2], acc[3]);
    o.z = pack_bf2(acc[4], acc[5]);
    o.w = pack_bf2(acc[6], acc[7]);
    __builtin_nontemporal_store(o, (uintx4*)hout + (unsigned)node * 16 + sub);
}

// ---- fused fc + LayerNorm via MFMA: one wave per 16-node tile ----
__global__ __launch_bounds__(256) void fcln_mfma_k(const unsigned* __restrict__ h,
                                                   const float* __restrict__ W,
                                                   const float* __restrict__ b,
                                                   const float* __restrict__ gamma,
                                                   const float* __restrict__ beta,
                                                   float* __restrict__ out) {
    int t = threadIdx.x;
    int wave = t >> 6, lane = t & 63;
    int m = lane & 15, quad = lane >> 4;
    int tile = blockIdx.x * 4 + wave;
    if (tile * 16 >= N_NODES) return;
    int node0 = tile * 16;

    short8 bfrag[3][4];
    float bias[3], gam[3], bet[3];
    #pragma unroll
    for (int ct = 0; ct < 3; ct++) {
        int c = ct * 16 + m;
        bool ok = (c < C_CLS);
        bias[ct] = ok ? b[c] : 0.0f;
        gam[ct]  = ok ? gamma[c] : 0.0f;
        bet[ct]  = ok ? beta[c] : 0.0f;
        #pragma unroll
        for (int ks = 0; ks < 4; ks++) {
            const float* wr = W + c * D_FEAT + ks * 32 + quad * 8;
            #pragma unroll
            for (int j = 0; j < 8; j++)
                bfrag[ct][ks][j] = ok ? bf16_of(wr[j]) : (short)0;
        }
    }

    floatx4 acc0 = {0.f,0.f,0.f,0.f}, acc1 = acc0, acc2 = acc0;
    #pragma unroll
    for (int ks = 0; ks < 4; ks++) {
        const uintx4* ap = (const uintx4*)&h[(node0 + m) * 64 + ks * 16 + quad * 4];
        uintx4 araw = __builtin_nontemporal_load(ap);
        short8 afrag;
        afrag[0] = (short)(araw.x & 0xffff); afrag[1] = (short)(araw.x >> 16);
        afrag[2] = (short)(araw.y & 0xffff); afrag[3] = (short)(araw.y >> 16);
        afrag[4] = (short)(araw.z & 0xffff); afrag[5] = (short)(araw.z >> 16);
        afrag[6] = (short)(araw.w & 0xffff); afrag[7] = (short)(araw.w >> 16);
        acc0 = __builtin_amdgcn_mfma_f32_16x16x32_bf16(afrag, bfrag[0][ks], acc0, 0, 0, 0);
        acc1 = __builtin_amdgcn_mfma_f32_16x16x32_bf16(afrag, bfrag[1][ks], acc1, 0, 0, 0);
        acc2 = __builtin_amdgcn_mfma_f32_16x16x32_bf16(afrag, bfrag[2][ks], acc2, 0, 0, 0);
    }

    #pragma unroll
    for (int r = 0; r < 4; r++) { acc0[r] += bias[0]; acc1[r] += bias[1]; acc2[r] += bias[2]; }

    float s[4], ss[4];
    #pragma unroll
    for (int r = 0; r < 4; r++) {
        s[r]  = acc0[r] + acc1[r] + acc2[r];
        ss[r] = acc0[r]*acc0[r] + acc1[r]*acc1[r] + acc2[r]*acc2[r];
    }
    #pragma unroll
    for (int o = 1; o < 16; o <<= 1) {
        #pragma unroll
        for (int r = 0; r < 4; r++) {
            s[r]  += __shfl_xor(s[r], o);
            ss[r] += __shfl_xor(ss[r], o);
        }
    }

    #pragma unroll
    for (int r = 0; r < 4; r++) {
        int node = node0 + quad * 4 + r;
        float mean = s[r] * (1.0f / C_CLS);
        float var  = ss[r] * (1.0f / C_CLS) - mean * mean;
        float inv  = rsqrtf(var + LN_EPS);
        float* orow = out + (size_t)node * C_CLS;
        __builtin_nontemporal_store((acc0[r] - mean) * inv * gam[0] + bet[0], orow + m);
        __builtin_nontemporal_store((acc1[r] - mean) * inv * gam[1] + bet[1], orow + 16 + m);
        if (m < 8)
            __builtin_nontemporal_store((acc2[r] - mean) * inv * gam[2] + bet[2], orow + 32 + m);
    }
}

// ---------------- launch ----------------
extern "C" void kernel_launch(void* const* d_in, const int* in_sizes, int n_in,
                              void* d_out, int out_size, void* d_ws, size_t ws_size,
                              hipStream_t stream) {
    const float* feat  = (const float*)d_in[0];
    const int*   row   = (const int*)d_in[1];
    const int*   col   = (const int*)d_in[2];
    const float* W     = (const float*)d_in[3];
    const float* b     = (const float*)d_in[4];
    const float* gamma = (const float*)d_in[5];
    const float* beta  = (const float*)d_in[6];
    float* out = (float*)d_out;

    char* ws = (char*)d_ws;
    size_t off = 0;
    auto alloc = [&](size_t bytes) {
        size_t o = off;
        off = (off + bytes + 255) & ~(size_t)255;
        return o;
    };
    float*    dinv     = (float*)   (ws + alloc((size_t)N_NODES * 4));
    float*    selfc    = (float*)   (ws + alloc((size_t)N_NODES * 4));
    int2*     rowinfo  = (int2*)    (ws + alloc((size_t)N_NODES * 8));
    int*      bktsz    = (int*)     (ws + alloc((size_t)NBKT * 4));
    int*      deg      = (int*)     (ws + alloc((size_t)N_NODES * 4));
    int*      csr_tmp  = (int*)     (ws + alloc((size_t)NBKT * BCAP * 4));
    int2*     csr      = (int2*)    (ws + alloc((size_t)NBKT * BCAP * 8));
    unsigned* h0       = (unsigned*)(ws + alloc((size_t)N_NODES * 64 * 4));
    unsigned* h1       = (unsigned*)(ws + alloc((size_t)N_NODES * 64 * 4));

    (void)hipMemsetAsync(bktsz, 0, (size_t)NBKT * 4, stream);
    (void)hipMemsetAsync(deg, 0, (size_t)N_NODES * 4, stream);

    convbin_k<<<EBLK + CONVB, 256, 0, stream>>>(feat, h0, row, col, bktsz, deg, csr_tmp);
    rowscan_k<<<NBKT, 256, 0, stream>>>(deg, rowinfo, dinv, selfc);
    refineB_k<<<NBKT, 256, 0, stream>>>(csr_tmp, bktsz, rowinfo, dinv, csr);

    int pgrid = N_NODES / 16;
    prop_bf_k<<<pgrid, 256, 0, stream>>>(h0, h1, rowinfo, csr, selfc);
    prop_bf_k<<<pgrid, 256, 0, stream>>>(h1, h0, rowinfo, csr, selfc);
    prop_bf_k<<<pgrid, 256, 0, stream>>>(h0, h1, rowinfo, csr, selfc);
    prop_bf_k<<<pgrid, 256, 0, stream>>>(h1, h0, rowinfo, csr, selfc);

    int tiles = N_NODES / 16;                       // 6250
    int fblocks = (tiles + 3) / 4;                  // 1563
    fcln_mfma_k<<<fblocks, 256, 0, stream>>>(h0, W, b, gamma, beta, out);
}

// Round 6
// 330.951 us; speedup vs baseline: 1.5665x; 1.5665x over previous
//
#include <hip/hip_runtime.h>
#include <hip/hip_fp16.h>

#define N_NODES 100000
#define N_EDGES 1600000
#define D_FEAT  128
#define C_CLS   40
#define ZSTRIDE 32                        // z row = 32 uints = 64 fp16 = 128 B
#define LN_EPS  1e-5f

#define RPB   256                         // rows per bucket
#define NBKT  ((N_NODES + RPB - 1) / RPB) // 391
#define BCAP  6144                        // padded slots/bucket (mean 4096, sigma~64)
#define TILE_E 4096                       // edges per bin block (round-0 proven)
#define EBLK  ((N_EDGES + TILE_E - 1) / TILE_E)  // 391
#define NTILES (N_NODES / 16)             // 6250 fc tiles
#define FCB   ((NTILES + 3) / 4)          // 1563 fc blocks

typedef __attribute__((ext_vector_type(8))) _Float16 half8;
typedef __attribute__((ext_vector_type(4))) float floatx4;
typedef __attribute__((ext_vector_type(2))) int   intx2;
typedef __attribute__((ext_vector_type(4))) unsigned uintx4;

// ---------- fp16 pair pack/unpack (storage only; accumulate fp32) ----------
__device__ inline float2 h2f2(unsigned v) {
    __half2 h = *(__half2*)&v;
    return __half22float2(h);
}
__device__ inline unsigned f2h2(float x, float y) {
    __half2 h = __floats2half2_rn(x, y);
    return *(unsigned*)&h;
}

// ---- fused: blocks [0,EBLK) bin edges into buckets (round-0 proven path);
// blocks [EBLK,EBLK+FCB) compute z0 = feat @ W^T via f16 MFMA (fc pulled
// BEFORE propagation: propagation is linear and commutes with W^T).
// csr_tmp[b*BCAP + slot] = (lrow<<17) | col
__global__ __launch_bounds__(256) void fcbin_k(const float* __restrict__ feat,
                                               const float* __restrict__ W,
                                               const int* __restrict__ row,
                                               const int* __restrict__ col,
                                               int* __restrict__ bktsz,
                                               int* __restrict__ csr_tmp,
                                               unsigned* __restrict__ z) {
    __shared__ int hist[NBKT];
    __shared__ int cbase[NBKT];
    __shared__ _Float16 zl[4][16][64];
    int t = threadIdx.x;
    if (blockIdx.x < EBLK) {
        // ---------------- edge binning ----------------
        int tile = blockIdx.x * TILE_E;
        for (int i = t; i < NBKT; i += 256) hist[i] = 0;
        __syncthreads();
        int r[16], c[16], pos[16];
        #pragma unroll
        for (int k = 0; k < 16; k++) {
            int e = tile + k * 256 + t;
            if (e < N_EDGES) {
                r[k] = row[e]; c[k] = col[e];
                pos[k] = atomicAdd(&hist[r[k] / RPB], 1);
            } else r[k] = -1;
        }
        __syncthreads();
        for (int i = t; i < NBKT; i += 256) {
            int h = hist[i];
            cbase[i] = h ? atomicAdd(&bktsz[i], h) : 0;
        }
        __syncthreads();
        #pragma unroll
        for (int k = 0; k < 16; k++) {
            if (r[k] >= 0) {
                int b = r[k] / RPB;
                int slot = cbase[b] + pos[k];
                if (slot < BCAP)   // statistically impossible overflow guard
                    csr_tmp[b * BCAP + slot] = ((r[k] & (RPB - 1)) << 17) | c[k];
            }
        }
        return;
    }
    // ---------------- fc: z = feat @ W^T (f16 MFMA, fp32 acc) ----------------
    int wave = t >> 6, lane = t & 63;
    int m = lane & 15, quad = lane >> 4;
    int tile = (blockIdx.x - EBLK) * 4 + wave;
    bool valid = (tile < NTILES);
    int node0 = tile * 16;

    half8 bfrag[3][4];
    if (valid) {
        #pragma unroll
        for (int ct = 0; ct < 3; ct++) {
            int c = ct * 16 + m;
            bool ok = (c < C_CLS);
            #pragma unroll
            for (int ks = 0; ks < 4; ks++) {
                const float* wr = W + c * D_FEAT + ks * 32 + quad * 8;
                #pragma unroll
                for (int j = 0; j < 8; j++)
                    bfrag[ct][ks][j] = ok ? (_Float16)wr[j] : (_Float16)0.0f;
            }
        }
    }

    floatx4 acc0 = {0.f,0.f,0.f,0.f}, acc1 = acc0, acc2 = acc0;
    if (valid) {
        #pragma unroll
        for (int ks = 0; ks < 4; ks++) {
            const float4* ap = (const float4*)&feat[(node0 + m) * D_FEAT + ks * 32 + quad * 8];
            float4 a0 = ap[0], a1 = ap[1];
            half8 afrag;
            afrag[0] = (_Float16)a0.x; afrag[1] = (_Float16)a0.y;
            afrag[2] = (_Float16)a0.z; afrag[3] = (_Float16)a0.w;
            afrag[4] = (_Float16)a1.x; afrag[5] = (_Float16)a1.y;
            afrag[6] = (_Float16)a1.z; afrag[7] = (_Float16)a1.w;
            acc0 = __builtin_amdgcn_mfma_f32_16x16x32_f16(afrag, bfrag[0][ks], acc0, 0, 0, 0);
            acc1 = __builtin_amdgcn_mfma_f32_16x16x32_f16(afrag, bfrag[1][ks], acc1, 0, 0, 0);
            acc2 = __builtin_amdgcn_mfma_f32_16x16x32_f16(afrag, bfrag[2][ks], acc2, 0, 0, 0);
        }
    }

    // zero pad cols 48..63 (cols 40..47 are exact 0 from zeroed bfrag)
    {
        int zr = lane >> 2;
        uint2 zz = make_uint2(0u, 0u);
        ((uint2*)&zl[wave][zr][48])[lane & 3] = zz;
    }
    // C/D layout: col = ct*16+m, row = quad*4+r
    if (valid) {
        #pragma unroll
        for (int r = 0; r < 4; r++) {
            int zrow = quad * 4 + r;
            zl[wave][zrow][m]      = (_Float16)acc0[r];
            zl[wave][zrow][16 + m] = (_Float16)acc1[r];
            zl[wave][zrow][32 + m] = (_Float16)acc2[r];
        }
    }
    __syncthreads();
    if (valid) {
        int zr = lane >> 2, part = lane & 3;
        uint4 v0 = ((uint4*)&zl[wave][zr][0])[part];
        uint4 v1 = ((uint4*)&zl[wave][zr][0])[part + 4];
        uint4* zg = (uint4*)z;
        zg[(size_t)(node0 + zr) * 8 + part]     = v0;
        zg[(size_t)(node0 + zr) * 8 + part + 4] = v1;
    }
}

// ---- refine A: per bucket, fine histogram + local scan -> rowinfo/dinv/selfc
// (round-3 proven, verbatim)
__global__ __launch_bounds__(256) void refineA_k(const int* __restrict__ csr_tmp,
                                                 const int* __restrict__ bktsz,
                                                 int2* __restrict__ rowinfo,
                                                 float* __restrict__ dinv,
                                                 float* __restrict__ selfc) {
    __shared__ int hist[RPB];
    __shared__ int psc[RPB];
    int b = blockIdx.x, t = threadIdx.x;
    int r0 = b * RPB;
    int nrows = min(RPB, N_NODES - r0);
    hist[t] = 0;
    __syncthreads();
    int cnt = bktsz[b];
    const int* base = csr_tmp + b * BCAP;
    for (int i = t; i < cnt; i += 256)
        atomicAdd(&hist[base[i] >> 17], 1);
    __syncthreads();
    int v = hist[t];
    psc[t] = v;
    __syncthreads();
    for (int off = 1; off < 256; off <<= 1) {
        int x = (t >= off) ? psc[t - off] : 0;
        __syncthreads();
        psc[t] += x;
        __syncthreads();
    }
    if (t < nrows) {
        int start = b * BCAP + psc[t] - v;     // exclusive prefix, bucket-local
        float d = rsqrtf((float)v + 1.0f);
        rowinfo[r0 + t] = make_int2(start, start + v);
        dinv[r0 + t]  = d;
        selfc[r0 + t] = 0.5f + 0.5f * d * d;
    }
}

// ---- refine B: scatter edges to final CSR with full weight (round-3 verbatim)
__global__ __launch_bounds__(256) void refineB_k(const int* __restrict__ csr_tmp,
                                                 const int* __restrict__ bktsz,
                                                 const int2* __restrict__ rowinfo,
                                                 const float* __restrict__ dinv,
                                                 int2* __restrict__ csr) {
    __shared__ int   cur[RPB];
    __shared__ float dl[RPB];
    int b = blockIdx.x, t = threadIdx.x;
    int r0 = b * RPB;
    int nrows = min(RPB, N_NODES - r0);
    if (t < nrows) {
        cur[t] = rowinfo[r0 + t].x;
        dl[t]  = dinv[r0 + t];
    }
    __syncthreads();
    int cnt = bktsz[b];
    const int* base = csr_tmp + b * BCAP;
    for (int i = t; i < cnt; i += 256) {
        int pk = base[i];
        int lr = pk >> 17;
        int c  = pk & 0x1FFFF;
        int p = atomicAdd(&cur[lr], 1);
        float w = (0.5f * dl[lr]) * dinv[c];
        csr[p] = make_int2(c, __float_as_int(w));
    }
}

// ---------------- propagation in 40-dim z space: 8 lanes per node
// (8 nodes/wave), 128 B/node payload — half the gather bytes of 128-dim.
__global__ __launch_bounds__(256) void prop_z_k(const unsigned* __restrict__ hin,
                                                unsigned* __restrict__ hout,
                                                const int2* __restrict__ rowinfo,
                                                const int2* __restrict__ csr,
                                                const float* __restrict__ selfc) {
    int t = threadIdx.x;
    int wave = t >> 6, lane = t & 63;
    int q   = lane >> 3;               // which of 8 nodes in the wave
    int sub = lane & 7;                // 8 lanes x uint4 = 128 B per node
    int node = blockIdx.x * 32 + wave * 8 + q;   // N % 32 == 0
    const uintx4* hin4 = (const uintx4*)hin;

    uintx4 hv = hin4[(unsigned)node * 8 + sub];
    float sc = selfc[node];
    float acc[8];
    {
        float2 f0 = h2f2(hv.x), f1 = h2f2(hv.y), f2 = h2f2(hv.z), f3 = h2f2(hv.w);
        acc[0] = f0.x * sc; acc[1] = f0.y * sc;
        acc[2] = f1.x * sc; acc[3] = f1.y * sc;
        acc[4] = f2.x * sc; acc[5] = f2.y * sc;
        acc[6] = f3.x * sc; acc[7] = f3.y * sc;
    }

    int2 ri = rowinfo[node];
    int j = ri.x, end = ri.y;
    int base = ri.x;                   // always a valid csr index for this row region

    int2 e[8];
    #pragma unroll
    for (int k = 0; k < 8; k++) {
        int idx = (j + k < end) ? j + k : base;
        e[k] = csr[idx];
    }

    while (__any(j < end)) {
        uintx4 g[8];
        float w[8];
        #pragma unroll
        for (int k = 0; k < 8; k++) {
            bool val = (j + k < end);
            int  c   = val ? e[k].x : 0;
            w[k]     = val ? __int_as_float(e[k].y) : 0.0f;
            g[k] = hin4[(unsigned)c * 8 + sub];
        }
        int j2 = j + 8;
        #pragma unroll
        for (int k = 0; k < 8; k++) {
            int idx = (j2 + k < end) ? j2 + k : base;
            e[k] = csr[idx];
        }
        #pragma unroll
        for (int k = 0; k < 8; k++) {
            float2 f0 = h2f2(g[k].x), f1 = h2f2(g[k].y), f2 = h2f2(g[k].z), f3 = h2f2(g[k].w);
            acc[0] += w[k] * f0.x; acc[1] += w[k] * f0.y;
            acc[2] += w[k] * f1.x; acc[3] += w[k] * f1.y;
            acc[4] += w[k] * f2.x; acc[5] += w[k] * f2.y;
            acc[6] += w[k] * f3.x; acc[7] += w[k] * f3.y;
        }
        j = j2;
    }

    uintx4 o;
    o.x = f2h2(acc[0], acc[1]);
    o.y = f2h2(acc[2], acc[3]);
    o.z = f2h2(acc[4], acc[5]);
    o.w = f2h2(acc[6], acc[7]);
    ((uintx4*)hout)[(unsigned)node * 8 + sub] = o;
}

// ---- final: bias + LayerNorm over 40 classes, fp32 out ----
// 4 threads per node; p=0,1 hold 16 cols each, p=2 holds 8, p=3 idle.
__global__ __launch_bounds__(256) void ln_k(const unsigned* __restrict__ z,
                                            const float* __restrict__ b,
                                            const float* __restrict__ gamma,
                                            const float* __restrict__ beta,
                                            float* __restrict__ out) {
    int t = threadIdx.x;
    int node = blockIdx.x * 64 + (t >> 2);
    int p = t & 2 ? (t & 3) : (t & 3);     // p = t & 3
    p = t & 3;
    if (node >= N_NODES) return;

    float v[16];
    float s = 0.0f, ss = 0.0f;
    int cb = p * 16;
    int nreal = (p < 2) ? 16 : (p == 2 ? 8 : 0);
    if (nreal) {
        const uint4* zr = (const uint4*)z + (size_t)node * 8;
        uint4 a0 = zr[p * 2], a1 = zr[p * 2 + 1];
        unsigned u[8] = {a0.x, a0.y, a0.z, a0.w, a1.x, a1.y, a1.z, a1.w};
        #pragma unroll
        for (int i = 0; i < 8; i++) {
            float2 f = h2f2(u[i]);
            v[2 * i] = f.x; v[2 * i + 1] = f.y;
        }
        for (int i = 0; i < nreal; i++) {
            v[i] += b[cb + i];
            s += v[i];
            ss += v[i] * v[i];
        }
    }
    s  += __shfl_xor(s, 1);  s  += __shfl_xor(s, 2);
    ss += __shfl_xor(ss, 1); ss += __shfl_xor(ss, 2);

    float mean = s * (1.0f / C_CLS);
    float var  = ss * (1.0f / C_CLS) - mean * mean;
    float inv  = rsqrtf(var + LN_EPS);
    if (nreal) {
        float* orow = out + (size_t)node * C_CLS + cb;
        for (int i = 0; i < nreal; i++)
            orow[i] = (v[i] - mean) * inv * gamma[cb + i] + beta[cb + i];
    }
}

// ---------------- launch ----------------
extern "C" void kernel_launch(void* const* d_in, const int* in_sizes, int n_in,
                              void* d_out, int out_size, void* d_ws, size_t ws_size,
                              hipStream_t stream) {
    const float* feat  = (const float*)d_in[0];
    const int*   row   = (const int*)d_in[1];
    const int*   col   = (const int*)d_in[2];
    const float* W     = (const float*)d_in[3];
    const float* b     = (const float*)d_in[4];
    const float* gamma = (const float*)d_in[5];
    const float* beta  = (const float*)d_in[6];
    float* out = (float*)d_out;

    char* ws = (char*)d_ws;
    size_t off = 0;
    auto alloc = [&](size_t bytes) {
        size_t o = off;
        off = (off + bytes + 255) & ~(size_t)255;
        return o;
    };
    float*    dinv     = (float*)   (ws + alloc((size_t)N_NODES * 4));
    float*    selfc    = (float*)   (ws + alloc((size_t)N_NODES * 4));
    int2*     rowinfo  = (int2*)    (ws + alloc((size_t)N_NODES * 8));
    int*      bktsz    = (int*)     (ws + alloc((size_t)NBKT * 4));
    int*      csr_tmp  = (int*)     (ws + alloc((size_t)NBKT * BCAP * 4));
    int2*     csr      = (int2*)    (ws + alloc((size_t)NBKT * BCAP * 8));
    unsigned* z0       = (unsigned*)(ws + alloc((size_t)N_NODES * ZSTRIDE * 4));
    unsigned* z1       = (unsigned*)(ws + alloc((size_t)N_NODES * ZSTRIDE * 4));

    (void)hipMemsetAsync(bktsz, 0, (size_t)NBKT * 4, stream);

    fcbin_k<<<EBLK + FCB, 256, 0, stream>>>(feat, W, row, col, bktsz, csr_tmp, z0);
    refineA_k<<<NBKT, 256, 0, stream>>>(csr_tmp, bktsz, rowinfo, dinv, selfc);
    refineB_k<<<NBKT, 256, 0, stream>>>(csr_tmp, bktsz, rowinfo, dinv, csr);

    int pgrid = N_NODES / 32;              // 3125
    prop_z_k<<<pgrid, 256, 0, stream>>>(z0, z1, rowinfo, csr, selfc);
    prop_z_k<<<pgrid, 256, 0, stream>>>(z1, z0, rowinfo, csr, selfc);
    prop_z_k<<<pgrid, 256, 0, stream>>>(z0, z1, rowinfo, csr, selfc);
    prop_z_k<<<pgrid, 256, 0, stream>>>(z1, z0, rowinfo, csr, selfc);

    int lblocks = (N_NODES + 63) / 64;     // 1563
    ln_k<<<lblocks, 256, 0, stream>>>(z0, b, gamma, beta, out);
}